// Round 1
// baseline (312.086 us; speedup 1.0000x reference)
//
#include <hip/hip_runtime.h>
#include <math.h>

#define DIM 128
#define HEADS 8
#define HD 16
#define NHS 32
#define NWS 32
#define NZS 8
#define NPOS 8192      // 32*32*8
#define EPS 1e-5f

// ---------------- instance-norm stats ----------------
// blocks 0..127   : x channels   (1024 elems each)
// blocks 128..255 : skip channels (8192 elems each)
// ws layout: [0,128) mu_x  [128,256) rs_x  [256,384) mu_s  [384,512) rs_s
__global__ __launch_bounds__(256) void stats_kernel(const float* __restrict__ x,
                                                    const float* __restrict__ skip,
                                                    float* __restrict__ ws) {
    int c = blockIdx.x;
    const float* src; int n; float* mu_out; float* rs_out; int ci;
    if (c < DIM) { ci = c; src = x + c * 1024; n = 1024; mu_out = ws; rs_out = ws + DIM; }
    else { ci = c - DIM; src = skip + (size_t)ci * NPOS; n = NPOS; mu_out = ws + 2*DIM; rs_out = ws + 3*DIM; }
    int t = threadIdx.x;
    float s = 0.f, s2 = 0.f;
    for (int i = t; i < n; i += 256) { float v = src[i]; s += v; s2 = fmaf(v, v, s2); }
    #pragma unroll
    for (int off = 32; off > 0; off >>= 1) {
        s  += __shfl_down(s,  off, 64);
        s2 += __shfl_down(s2, off, 64);
    }
    __shared__ float ls[4], ls2[4];
    int wv = t >> 6;
    if ((t & 63) == 0) { ls[wv] = s; ls2[wv] = s2; }
    __syncthreads();
    if (t == 0) {
        float S  = ls[0] + ls[1] + ls[2] + ls[3];
        float S2 = ls2[0] + ls2[1] + ls2[2] + ls2[3];
        float inv_n = 1.f / (float)n;
        float mu  = S * inv_n;
        float var = S2 * inv_n - mu * mu;
        mu_out[ci] = mu;
        rs_out[ci] = rsqrtf(var + EPS);
    }
}

// ---------------- q/k/v projections ----------------
// grid (128, 3): blockIdx.x = 64-position tile, blockIdx.y = {q,k,v}
// A-tile staged normalized in LDS (row stride 129 -> 2-way bank alias, free).
// thread t: ln = t&63 (position), ch = t>>6; computes 32 consecutive out channels.
__global__ __launch_bounds__(256) void qkv_kernel(const float* __restrict__ x,
                                                  const float* __restrict__ skip,
                                                  const float* __restrict__ Wq, const float* __restrict__ bq,
                                                  const float* __restrict__ Wk, const float* __restrict__ bk,
                                                  const float* __restrict__ Wv, const float* __restrict__ bv,
                                                  const float* __restrict__ ws,
                                                  float* __restrict__ q_out,
                                                  float* __restrict__ k_out,
                                                  float* __restrict__ v_out) {
    __shared__ float a[64 * 129];
    int t = threadIdx.x;
    int which = blockIdx.y;
    int n0 = blockIdx.x * 64;

    if (which == 0) {
        const float* mu = ws;       const float* rs = ws + DIM;
        for (int idx = t; idx < 8192; idx += 256) {
            int ci = idx >> 6, ln = idx & 63;
            int n = n0 + ln;
            int hc = n >> 8, wc = (n >> 3) & 31, zc = n & 7;
            float v = x[ci * 1024 + (hc >> 1) * 64 + (wc >> 1) * 4 + (zc >> 1)];
            a[ln * 129 + ci] = (v - mu[ci]) * rs[ci];
        }
    } else {
        const float* mu = ws + 2*DIM; const float* rs = ws + 3*DIM;
        for (int idx = t; idx < 8192; idx += 256) {
            int ci = idx >> 6, ln = idx & 63;
            float v = skip[(size_t)ci * NPOS + n0 + ln];
            a[ln * 129 + ci] = (v - mu[ci]) * rs[ci];
        }
    }
    __syncthreads();

    const float* W  = (which == 0) ? Wq : (which == 1) ? Wk : Wv;
    const float* b  = (which == 0) ? bq : (which == 1) ? bk : bv;
    float* outp     = (which == 0) ? q_out : (which == 1) ? k_out : v_out;
    float scale     = (which == 0) ? 0.25f : 1.0f;   // HEAD_DIM^-0.5, applied after bias (matches ref)

    int ln = t & 63, ch = t >> 6;
    float acc[32];
    #pragma unroll
    for (int j = 0; j < 32; ++j) acc[j] = b[ch * 32 + j];
    for (int ci = 0; ci < 128; ++ci) {
        float av = a[ln * 129 + ci];
        const float4* wr = (const float4*)(W + ci * 128 + ch * 32);
        #pragma unroll
        for (int j4 = 0; j4 < 8; ++j4) {
            float4 w4 = wr[j4];
            acc[j4*4 + 0] = fmaf(av, w4.x, acc[j4*4 + 0]);
            acc[j4*4 + 1] = fmaf(av, w4.y, acc[j4*4 + 1]);
            acc[j4*4 + 2] = fmaf(av, w4.z, acc[j4*4 + 2]);
            acc[j4*4 + 3] = fmaf(av, w4.w, acc[j4*4 + 3]);
        }
    }
    float* op = outp + (size_t)(n0 + ln) * 128 + ch * 32;
    #pragma unroll
    for (int j = 0; j < 32; j += 4) {
        float4 vv = make_float4(acc[j] * scale, acc[j+1] * scale, acc[j+2] * scale, acc[j+3] * scale);
        *(float4*)(op + j) = vv;
    }
}

// ---------------- neighborhood attention (online softmax) ----------------
// 1 thread per (n, head). 65536 threads total.
__global__ __launch_bounds__(256) void attn_kernel(const float* __restrict__ q,
                                                   const float* __restrict__ k,
                                                   const float* __restrict__ v,
                                                   const float* __restrict__ rpb,
                                                   float* __restrict__ ao) {
    int g = blockIdx.x * 256 + threadIdx.x;
    int h = g & 7, n = g >> 3;
    int hc = n >> 8, wc = (n >> 3) & 31, zc = n & 7;

    float qv[16];
    #pragma unroll
    for (int i = 0; i < 4; ++i)
        ((float4*)qv)[i] = ((const float4*)(q + (size_t)n * 128 + h * 16))[i];

    float o[16];
    #pragma unroll
    for (int d = 0; d < 16; ++d) o[d] = 0.f;
    float m = -1e30f, l = 0.f;

    int sh = min(max(hc - 2, 0), 27);
    int sw = min(max(wc - 2, 0), 27);
    int sz = min(max(zc - 2, 0), 3);
    const float* rp = rpb + h * 729;

    for (int jh = 0; jh < 5; ++jh) {
        int nh = sh + jh;
        int bh = (nh - hc + 4) * 81;
        int nbh = nh * 256;
        for (int jw = 0; jw < 5; ++jw) {
            int nw = sw + jw;
            int bw = bh + (nw - wc + 4) * 9;
            int nbw = nbh + nw * 8;
            #pragma unroll
            for (int jz = 0; jz < 5; ++jz) {
                int nz = sz + jz;
                int nbr = nbw + nz;
                const float* kp = k + (size_t)nbr * 128 + h * 16;
                const float* vp = v + (size_t)nbr * 128 + h * 16;
                float kv[16], vv[16];
                #pragma unroll
                for (int i = 0; i < 4; ++i) ((float4*)kv)[i] = ((const float4*)kp)[i];
                #pragma unroll
                for (int i = 0; i < 4; ++i) ((float4*)vv)[i] = ((const float4*)vp)[i];
                // 4-way split dot to shorten dependency chain (occupancy is low here)
                float d0 = 0.f, d1 = 0.f, d2 = 0.f, d3 = 0.f;
                #pragma unroll
                for (int d = 0; d < 4; ++d) {
                    d0 = fmaf(qv[d],      kv[d],      d0);
                    d1 = fmaf(qv[d + 4],  kv[d + 4],  d1);
                    d2 = fmaf(qv[d + 8],  kv[d + 8],  d2);
                    d3 = fmaf(qv[d + 12], kv[d + 12], d3);
                }
                float s = (d0 + d1) + (d2 + d3) + rp[bw + nz - zc + 4];
                float mn = fmaxf(m, s);
                float sc = __expf(m - mn);
                float p  = __expf(s - mn);
                l = fmaf(l, sc, p);
                #pragma unroll
                for (int d = 0; d < 16; ++d) o[d] = fmaf(o[d], sc, p * vv[d]);
                m = mn;
            }
        }
    }
    float inv = 1.f / l;
    float r[16];
    #pragma unroll
    for (int d = 0; d < 16; ++d) r[d] = o[d] * inv;
    #pragma unroll
    for (int i = 0; i < 4; ++i)
        ((float4*)(ao + (size_t)n * 128 + h * 16))[i] = ((float4*)r)[i];
}

// ---------------- output projection + transpose to (C, H, W, Z) ----------------
__global__ __launch_bounds__(256) void proj_kernel(const float* __restrict__ ao,
                                                   const float* __restrict__ Wo,
                                                   const float* __restrict__ bo,
                                                   float* __restrict__ out) {
    __shared__ float a[64 * 129];
    int t = threadIdx.x;
    int n0 = blockIdx.x * 64;
    for (int idx = t; idx < 8192; idx += 256) {
        int ln = idx >> 7, ci = idx & 127;
        a[ln * 129 + ci] = ao[(size_t)n0 * 128 + idx];
    }
    __syncthreads();

    int ln = t & 63, ch = t >> 6;
    float acc[32];
    #pragma unroll
    for (int j = 0; j < 32; ++j) acc[j] = bo[ch * 32 + j];
    for (int ci = 0; ci < 128; ++ci) {
        float av = a[ln * 129 + ci];
        const float4* wr = (const float4*)(Wo + ci * 128 + ch * 32);
        #pragma unroll
        for (int j4 = 0; j4 < 8; ++j4) {
            float4 w4 = wr[j4];
            acc[j4*4 + 0] = fmaf(av, w4.x, acc[j4*4 + 0]);
            acc[j4*4 + 1] = fmaf(av, w4.y, acc[j4*4 + 1]);
            acc[j4*4 + 2] = fmaf(av, w4.z, acc[j4*4 + 2]);
            acc[j4*4 + 3] = fmaf(av, w4.w, acc[j4*4 + 3]);
        }
    }
    // out[c][n] : lanes (ln) consecutive in n -> coalesced stores
    #pragma unroll
    for (int j = 0; j < 32; ++j)
        out[(size_t)(ch * 32 + j) * NPOS + n0 + ln] = acc[j];
}

extern "C" void kernel_launch(void* const* d_in, const int* in_sizes, int n_in,
                              void* d_out, int out_size, void* d_ws, size_t ws_size,
                              hipStream_t stream) {
    const float* x    = (const float*)d_in[0];
    const float* skip = (const float*)d_in[1];
    const float* Wq   = (const float*)d_in[2];
    const float* bq   = (const float*)d_in[3];
    const float* Wk   = (const float*)d_in[4];
    const float* bk   = (const float*)d_in[5];
    const float* Wv   = (const float*)d_in[6];
    const float* bv   = (const float*)d_in[7];
    const float* rpb  = (const float*)d_in[8];
    const float* Wo   = (const float*)d_in[9];
    const float* bo   = (const float*)d_in[10];
    float* out = (float*)d_out;

    float* ws  = (float*)d_ws;            // 512 floats of norm stats
    float* q   = ws + 512;                // 8192*128
    float* k   = q  + (size_t)NPOS * 128; // 8192*128
    float* v   = k  + (size_t)NPOS * 128; // 8192*128
    float* ao  = v  + (size_t)NPOS * 128; // 8192*128

    stats_kernel<<<256, 256, 0, stream>>>(x, skip, ws);
    qkv_kernel<<<dim3(128, 3), 256, 0, stream>>>(x, skip, Wq, bq, Wk, bk, Wv, bv, ws, q, k, v);
    attn_kernel<<<256, 256, 0, stream>>>(q, k, v, rpb, ao);
    proj_kernel<<<128, 256, 0, stream>>>(ao, Wo, bo, out);
}